// Round 6
// baseline (741.879 us; speedup 1.0000x reference)
//
#include <hip/hip_runtime.h>
#include <cstdint>

#define M_DIM 16384
#define N_DIM 4096
#define K_DIM 4096

// 256x256 tile, BK=128 int8 (128B rows), 8 waves (2M x 4N), 4-window
// schedule with one-window read-ahead (ds_reads overlap MFMA).
#define BM 256
#define BN 256
#define BK 128

typedef __attribute__((ext_vector_type(4))) int int32x4;
typedef __attribute__((ext_vector_type(4))) float f32x4;

#define GLLD16(g, l)                                              \
  __builtin_amdgcn_global_load_lds(                               \
      (const __attribute__((address_space(1))) void*)(g),         \
      (__attribute__((address_space(3))) void*)(l), 16, 0, 0)

// ---------------------------------------------------------------------------
// Fused quantization kernel (verified r5). Blocks [0,16384): activations;
// [16384,20480): one weight row each (+ wsum -> cs/off).
// ---------------------------------------------------------------------------
__global__ void quant_fused(const float* __restrict__ x,
                            const float* __restrict__ w,
                            const float* __restrict__ wscale,
                            const float* __restrict__ bias,
                            const float* __restrict__ sp,
                            const int* __restrict__ zpp,
                            int8_t* __restrict__ qx,
                            int8_t* __restrict__ qw,
                            float* __restrict__ cs,
                            float* __restrict__ off) {
  __shared__ int red[4];
  if (blockIdx.x < 16384) {
    const float rs = 1.0f / sp[0];
    const int zp = zpp[0];
    const size_t b = (size_t)blockIdx.x * 1024;
    const f32x4* x4 = (const f32x4*)x;
    unsigned* q4 = (unsigned*)qx;
#pragma unroll
    for (int i = 0; i < 4; i++) {
      const size_t idx = b + (size_t)i * 256 + threadIdx.x;
      f32x4 v = __builtin_nontemporal_load(&x4[idx]);
      int q0 = min(127, max(-128, (int)rintf(v[0] * rs) + zp));
      int q1 = min(127, max(-128, (int)rintf(v[1] * rs) + zp));
      int q2 = min(127, max(-128, (int)rintf(v[2] * rs) + zp));
      int q3 = min(127, max(-128, (int)rintf(v[3] * rs) + zp));
      q4[idx] = (unsigned)(q0 & 255) | ((unsigned)(q1 & 255) << 8) |
                ((unsigned)(q2 & 255) << 16) | ((unsigned)(q3 & 255) << 24);
    }
  } else {
    const int n = blockIdx.x - 16384;
    const float ws = wscale[n];
    const float rws = 1.0f / ws;
    const float s = sp[0];
    const int zp = zpp[0];
    const f32x4* wr = (const f32x4*)(w + (size_t)n * K_DIM);
    unsigned* qr = (unsigned*)(qw + (size_t)n * K_DIM);
    int sum = 0;
#pragma unroll
    for (int it = 0; it < K_DIM / (256 * 4); it++) {
      const int idx = it * 256 + threadIdx.x;
      f32x4 v = __builtin_nontemporal_load(&wr[idx]);
      int q0 = min(127, max(-128, (int)rintf(v[0] * rws)));
      int q1 = min(127, max(-128, (int)rintf(v[1] * rws)));
      int q2 = min(127, max(-128, (int)rintf(v[2] * rws)));
      int q3 = min(127, max(-128, (int)rintf(v[3] * rws)));
      sum += q0 + q1 + q2 + q3;
      qr[idx] = (unsigned)(q0 & 255) | ((unsigned)(q1 & 255) << 8) |
                ((unsigned)(q2 & 255) << 16) | ((unsigned)(q3 & 255) << 24);
    }
#pragma unroll
    for (int o = 32; o > 0; o >>= 1) sum += __shfl_down(sum, o, 64);
    if ((threadIdx.x & 63) == 0) red[threadIdx.x >> 6] = sum;
    __syncthreads();
    if (threadIdx.x == 0) {
      const int tot = red[0] + red[1] + red[2] + red[3];
      const float c = s * ws;
      cs[n] = c;
      off[n] = bias[n] - (float)(zp * tot) * c;
    }
  }
}

// ---------------------------------------------------------------------------
// Kernel: int8 GEMM. Data movement / LDS layout / swizzles / acc mapping /
// epilogue byte-identical to verified r3/r5. Change: fragment ds_reads are
// issued ONE WINDOW EARLY, overlapping the MFMA clusters (r5 PMC showed
// reads and MFMAs serialized: 5270cy LDS + 5225cy MFMA ~= 9860cy/iter).
// A-frags ping-pong afA/afB per window; B-frags reload in place after last
// consuming MFMA (W1/W2 share tile-e B, W3/W4 share tile-o B).
//
// Stage plan per iter (unchanged): W1: buf1.A.h1<-t(2i+1) [2 glld];
// W2: buf0.{A.h0,B.h0,B.h1}<-t(2i+2) [6]; W3: buf0.A.h1<-t(2i+2) [2];
// W4: buf1.{A.h0,B.h0,B.h1}<-t(2i+3) [6].
//
// Publication ledger (region drained+barriered BEFORE its read issues):
//  reads issued in W4 (for next W1): buf0.{A.h0,B.*} staged W2 -> need W2
//    drained by end-W3: outstanding there = W2(6)+W3(2) -> VM(2) OK
//  reads in W1 (for W2): buf0.A.h1 staged prevW3 -> drained by end-prevW4:
//    outstanding = W3(2)+W4(6) -> VM(6) OK
//  reads in W2 (for W3): buf1.{A.h0,B.*} staged prevW4 -> drained by
//    end-W1: outstanding = prevW4(6)+W1(2) -> VM(2) OK
//  reads in W3 (for W4): buf1.A.h1 staged W1 -> drained by end-W2:
//    outstanding = W1(2)+W2(6) -> VM(6) OK
// Drains: end-W1 VM(2), end-W2 VM(6), end-W3 VM(2), end-W4 VM(6); each
// waits only on stages 2 windows old -> ~zero stall.
// Overwrite ledger (stage vs reads of same region): every stage is >=1
// barrier after the entry-lgkmcnt(0) that drained those reads (W2 stages
// buf0.h0/B read-drained at entry-W1; W3: drained entry-W2; W4: entry-W3;
// W1: entry-prevW4). OK.
// Read pinning: C-level ds_reads can't cross windows -- every BAR() is
// bracketed by asm-volatile memory-clobber waitcnts (VM before, WAITLGKM
// after), same property that held r1-r5 correct.
// ---------------------------------------------------------------------------
__global__ __launch_bounds__(512, 2) void gemm_i8(
    const int8_t* __restrict__ qx, const int8_t* __restrict__ qw,
    const float* __restrict__ cs, const float* __restrict__ off,
    float* __restrict__ out) {
  __shared__ __align__(16) int8_t lds[131072];

  const int tid = threadIdx.x;
  const int lane = tid & 63;
  const int wave = tid >> 6;  // 0..7
  const int wm = wave >> 2;   // 0..1  (128 rows each)
  const int wn = wave & 3;    // 0..3  (64 cols each)

  // T1: XCD-aware swizzle, nwg=1024 (%8==0 -> bijective)
  const int bid = blockIdx.x;
  const int swz = (bid & 7) * 128 + (bid >> 3);
  const int n0 = (swz & 15) * BN;
  const int m0 = (swz >> 4) * BM;

  int32x4 acc[8][4] = {};
  int32x4 afA[8], afB[8], bf0[4], bf1[4];

  // ---- staging source pointers (2 glld per wave per half; lane-linear LDS
  // dest; inverse-swizzled global source) ----
  const int scol = ((lane & 7) ^ ((lane >> 3) & 7)) * 16;
  const int8_t* pA[2][2];
  const int8_t* pB[2][2];
#pragma unroll
  for (int h = 0; h < 2; h++)
#pragma unroll
    for (int j = 0; j < 2; j++) {
      const int r = h * 128 + (wave * 2 + j) * 8 + (lane >> 3);  // lds row
      const int ga = ((r >> 6) & 1) * 128 + (r >> 7) * 64 + (r & 63);
      const int gb = ((r >> 5) & 3) * 64 + (r >> 7) * 32 + (r & 31);
      pA[h][j] = qx + (size_t)(m0 + ga) * K_DIM + scol;
      pB[h][j] = qw + (size_t)(n0 + gb) * K_DIM + scol;
    }

  // ---- fragment read offsets ----
  const int fr = lane & 15;
  const int quad = lane >> 4;
  int aoffs[8], boffs[4];
#pragma unroll
  for (int mtl = 0; mtl < 4; mtl++)
#pragma unroll
    for (int ks = 0; ks < 2; ks++) {
      const int r = wm * 64 + mtl * 16 + fr;
      const int c = (ks * 4 + quad) ^ (fr & 7);
      aoffs[mtl * 2 + ks] = r * 128 + c * 16;
    }
#pragma unroll
  for (int ntl = 0; ntl < 2; ntl++)
#pragma unroll
    for (int ks = 0; ks < 2; ks++) {
      const int r = wn * 32 + ntl * 16 + fr;
      const int c = (ks * 4 + quad) ^ (fr & 7);
      boffs[ntl * 2 + ks] = r * 128 + c * 16;
    }

#define STAGE(rbase, h, P, kb)                                          \
  do {                                                                  \
    GLLD16(P[h][0] + (kb), lds + (rbase) + (h) * 16384 + wave * 2048);  \
    GLLD16(P[h][1] + (kb),                                              \
           lds + (rbase) + (h) * 16384 + wave * 2048 + 1024);           \
  } while (0)

#define LDA(buf, h, AF)                                                 \
  do {                                                                  \
    _Pragma("unroll") for (int q = 0; q < 8; q++) AF[q] =               \
        *(const int32x4*)(lds + (buf) * 65536 + (h) * 16384 + aoffs[q]); \
  } while (0)

#define LDB(buf, g, BF)                                                 \
  do {                                                                  \
    _Pragma("unroll") for (int q = 0; q < 4; q++) BF[q] =               \
        *(const int32x4*)(lds + (buf) * 65536 + 32768 + (g) * 16384 +   \
                          boffs[q]);                                    \
  } while (0)

// Swapped operands (verified r3): A-op = qw frag (lane dim -> D reg = N),
// B-op = qx frag (lane dim -> D lane = M).
#define MM(h, g, BF, AF)                                                   \
  do {                                                                    \
    _Pragma("unroll") for (int mtl = 0; mtl < 4; mtl++)                   \
        _Pragma("unroll") for (int ntl = 0; ntl < 2; ntl++) {             \
      acc[(h)*4 + mtl][(g)*2 + ntl] = __builtin_amdgcn_mfma_i32_16x16x64_i8( \
          BF[ntl * 2 + 0], AF[mtl * 2 + 0], acc[(h)*4 + mtl][(g)*2 + ntl], \
          0, 0, 0);                                                        \
      acc[(h)*4 + mtl][(g)*2 + ntl] = __builtin_amdgcn_mfma_i32_16x16x64_i8( \
          BF[ntl * 2 + 1], AF[mtl * 2 + 1], acc[(h)*4 + mtl][(g)*2 + ntl], \
          0, 0, 0);                                                        \
    }                                                                      \
  } while (0)

#define BAR() __builtin_amdgcn_s_barrier()
#define WAITLGKM() asm volatile("s_waitcnt lgkmcnt(0)" ::: "memory")
#define VM2() asm volatile("s_waitcnt vmcnt(2)" ::: "memory")
#define VM6() asm volatile("s_waitcnt vmcnt(6)" ::: "memory")
#define PRIO(x) __builtin_amdgcn_s_setprio(x)

  // ---- prologue: buf0 full (8 glld, t0) + buf1 minus A.h1 (6 glld, t1);
  // VM(6) drains buf0's 8 -> publishes everything W1 reads AND W1's
  // read-ahead region (buf0.A.h1). Then pre-load W1's entry frags.
  STAGE(0, 0, pA, 0);
  STAGE(0, 1, pA, 0);
  STAGE(32768, 0, pB, 0);
  STAGE(32768, 1, pB, 0);
  STAGE(65536, 0, pA, 128);
  STAGE(98304, 0, pB, 128);
  STAGE(98304, 1, pB, 128);
  VM6();
  BAR();
  LDA(0, 0, afA);
  LDB(0, 0, bf0);
  LDB(0, 1, bf1);

  for (int i = 0; i < K_DIM / (2 * BK); i++) {
    const int kb1 = ((2 * i + 1) << 7) & (K_DIM - 1);
    const int kb2 = ((2 * i + 2) << 7) & (K_DIM - 1);
    const int kb3 = ((2 * i + 3) << 7) & (K_DIM - 1);
    // ---- W1: compute e.h0 (afA, bf0, bf1); read-ahead W2's A (afB);
    //      stage buf1.A.h1 <- t(2i+1)
    WAITLGKM();
    STAGE(65536, 1, pA, kb1);
    LDA(0, 1, afB);
    PRIO(1); MM(0, 0, bf0, afA); PRIO(0);
    PRIO(1); MM(0, 1, bf1, afA); PRIO(0);
    VM2();
    BAR();
    // ---- W2: compute e.h1 (afB, bf1, bf0); read-ahead W3 frags (afA +
    //      B reloads after last use); stage buf0.{A.h0,B.h0,B.h1} <- t(2i+2)
    WAITLGKM();
    STAGE(0, 0, pA, kb2);
    STAGE(32768, 0, pB, kb2);
    STAGE(32768, 1, pB, kb2);
    LDA(1, 0, afA);
    PRIO(1); MM(1, 1, bf1, afB); PRIO(0);
    LDB(1, 1, bf1);
    PRIO(1); MM(1, 0, bf0, afB); PRIO(0);
    LDB(1, 0, bf0);
    VM6();
    BAR();
    // ---- W3: compute o.h0 (afA, bf0, bf1); read-ahead W4's A (afB);
    //      stage buf0.A.h1 <- t(2i+2)
    WAITLGKM();
    STAGE(0, 1, pA, kb2);
    LDA(1, 1, afB);
    PRIO(1); MM(0, 0, bf0, afA); PRIO(0);
    PRIO(1); MM(0, 1, bf1, afA); PRIO(0);
    VM2();
    BAR();
    // ---- W4: compute o.h1 (afB, bf1, bf0); read-ahead next-W1 frags
    //      (afA + B reloads); stage buf1.{A.h0,B.h0,B.h1} <- t(2i+3)
    WAITLGKM();
    STAGE(65536, 0, pA, kb3);
    STAGE(98304, 0, pB, kb3);
    STAGE(98304, 1, pB, kb3);
    LDA(0, 0, afA);
    PRIO(1); MM(1, 1, bf1, afB); PRIO(0);
    LDB(0, 1, bf1);
    PRIO(1); MM(1, 0, bf0, afB); PRIO(0);
    LDB(0, 0, bf0);
    VM6();
    BAR();
  }

  // ---- epilogue (verified r3): lane holds 4 consecutive N-cols per tile ->
  // f32x4 NT stores. n = colb + reg, m = row-base + fr (lane).
#pragma unroll
  for (int nt = 0; nt < 4; nt++) {
    const int colb = n0 + wn * 64 + nt * 16 + quad * 4;
    const f32x4 c4 = *(const f32x4*)(cs + colb);
    const f32x4 o4 = *(const f32x4*)(off + colb);
#pragma unroll
    for (int mt = 0; mt < 8; mt++) {
      const int row = m0 + wm * 128 + mt * 16 + fr;
      f32x4 v;
      v[0] = (float)acc[mt][nt][0] * c4[0] + o4[0];
      v[1] = (float)acc[mt][nt][1] * c4[1] + o4[1];
      v[2] = (float)acc[mt][nt][2] * c4[2] + o4[2];
      v[3] = (float)acc[mt][nt][3] * c4[3] + o4[3];
      __builtin_nontemporal_store(
          v, (f32x4*)(out + (size_t)row * N_DIM + colb));
    }
  }
#undef STAGE
#undef LDA
#undef LDB
#undef MM
#undef BAR
#undef WAITLGKM
#undef VM2
#undef VM6
#undef PRIO
}

// ---------------------------------------------------------------------------
extern "C" void kernel_launch(void* const* d_in, const int* in_sizes, int n_in,
                              void* d_out, int out_size, void* d_ws,
                              size_t ws_size, hipStream_t stream) {
  const float* x = (const float*)d_in[0];
  const float* w = (const float*)d_in[1];
  const float* bias = (const float*)d_in[2];
  const float* act_scale = (const float*)d_in[3];
  const int* zp = (const int*)d_in[4];
  const float* wscale = (const float*)d_in[5];
  float* out = (float*)d_out;

  int8_t* qx = (int8_t*)d_ws;                          // 64 MB
  int8_t* qw = qx + (size_t)M_DIM * K_DIM;             // 16 MB
  float* cs = (float*)(qw + (size_t)N_DIM * K_DIM);    // 16 KB
  float* off = cs + N_DIM;                             // 16 KB

  quant_fused<<<16384 + N_DIM, 256, 0, stream>>>(x, w, wscale, bias,
                                                 act_scale, zp, qx, qw, cs,
                                                 off);
  gemm_i8<<<dim3((M_DIM / BM) * (N_DIM / BN)), 512, 0, stream>>>(qx, qw, cs,
                                                                 off, out);
}